// Round 4
// baseline (138.489 us; speedup 1.0000x reference)
//
#include <hip/hip_runtime.h>

#define EPS 1e-5f

typedef float f4 __attribute__((ext_vector_type(4)));

// Broadcast a block-uniform load into an SGPR (weights, scalars).
__device__ __forceinline__ float uload(const float* __restrict__ p) {
  return __int_as_float(__builtin_amdgcn_readfirstlane(__float_as_int(*p)));
}

// ---------------------------------------------------------------------------
// K12: fused conv1(1->8)+ReLU+pool + conv2(4 used oc of 16)+ReLU+pool + sum.
// Block = (batch b, quarter q): pooled2 rows 8q..8q+7, 256 threads.
// TWO channel passes (g=0: ch 0-3, g=1: ch 4-7) so p1 is half-size and both
// the x tile AND p1 fit in 40.3 KB LDS -> 4 blocks/CU (16 waves/CU), while
// all conv reads come from LDS with zero per-position bounds checks.
// conv2 partial sums accumulate in registers across the two passes; ReLU+pool
// applied after the full 8-ic sum, so results are exact fp32.
// ---------------------------------------------------------------------------
__global__ __launch_bounds__(256, 4) void k12_fused(
    const float* __restrict__ x, const float* __restrict__ w1,
    const float* __restrict__ b1, const float* __restrict__ w2,
    const float* __restrict__ b2, float* __restrict__ partials) {
  __shared__ float xt[38][132];     // x rows 32q-3 .. 32q+34, col i = x col i-1
  __shared__ float p1[4][18][66];   // one 4-channel group of pooled1
  __shared__ float w2s[292];        // w2[0:4][0:8][9] (288) + b2[0:4]
  __shared__ float wred[4][4];

  const int q   = blockIdx.x & 3;
  const int b   = blockIdx.x >> 2;
  const int tid = threadIdx.x;
  const float* xb = x + (size_t)b * (128 * 128);

  // ---- stage conv2 weights (first 4 oc = first 288 floats) + biases ----
  w2s[tid < 288 ? tid : 0] = w2[tid < 288 ? tid : 0];  // tid 0..255 (re-write ok)
  if (tid < 32) w2s[256 + tid] = w2[256 + tid];
  if (tid < 4)  w2s[288 + tid] = b2[tid];

  // ---- zero p1's SAME-padding halo columns (never overwritten) ----
  if (tid < 72) {
    int ic = tid / 18, gl = tid - ic * 18;
    p1[ic][gl][0]  = 0.f;
    p1[ic][gl][65] = 0.f;
  }

  // ---- stage x tile: rows 32q-3 .. 32q+34, zero-padded (bounds here ONLY) --
  {
    const int xr0 = 32 * q - 3;
    int r = tid / 132, c = tid - r * 132;
#pragma unroll
    for (int it = 0; it < 20; ++it) {  // 20*256 = 5120 >= 38*132 = 5016
      if (r < 38) {
        int gy = xr0 + r, gc = c - 1;
        float v = 0.f;
        if (gy >= 0 && gy < 128 && gc >= 0 && gc < 128) v = xb[gy * 128 + gc];
        xt[r][c] = v;
      }
      r += 1; c += 124;                 // advance by 256 = 132 + 124
      if (c >= 132) { c -= 132; r += 1; }
    }
  }
  __syncthreads();

  // conv2 accumulators (bias-initialized once; summed across both passes)
  float acc[4][2][2];
#pragma unroll
  for (int oc = 0; oc < 4; ++oc) {
    float bias = w2s[288 + oc];
    acc[oc][0][0] = bias; acc[oc][0][1] = bias;
    acc[oc][1][0] = bias; acc[oc][1][1] = bias;
  }

  const int px2  = tid & 31;
  const int py2l = tid >> 5;  // 0..7

#pragma unroll 1
  for (int g = 0; g < 2; ++g) {
    if (g) __syncthreads();  // pass-0 conv2 reads done before overwriting p1

    // conv1 weights for this 4-channel group -> SGPRs
    float wv1[4][9], bb1[4];
#pragma unroll
    for (int oc = 0; oc < 4; ++oc) {
#pragma unroll
      for (int k = 0; k < 9; ++k) wv1[oc][k] = uload(w1 + (4 * g + oc) * 9 + k);
      bb1[oc] = uload(b1 + 4 * g + oc);
    }

    // ---- conv1 + ReLU + 2x2 pool -> p1[oc'][gl][px+1], gl = 0..17 ----
    // pooled1 row G = 16q-1+gl uses xt rows 2gl..2gl+3 (xt row 0 = x row 2G-1)
#pragma unroll 1
    for (int pos = tid; pos < 18 * 64; pos += 256) {
      const int gl = pos >> 6, px = pos & 63;
      const int G = 16 * q - 1 + gl;
      const bool validG = (G >= 0) && (G < 64);
      float xin[4][4];
#pragma unroll
      for (int r = 0; r < 4; ++r)
#pragma unroll
        for (int c = 0; c < 4; ++c)
          xin[r][c] = xt[2 * gl + r][2 * px + c];  // stride-2 lanes: free 2-way
#pragma unroll
      for (int oc = 0; oc < 4; ++oc) {
        float best = 0.f;  // ReLU floor
#pragma unroll
        for (int dy = 0; dy < 2; ++dy)
#pragma unroll
          for (int dx = 0; dx < 2; ++dx) {
            float a = bb1[oc];
#pragma unroll
            for (int ky = 0; ky < 3; ++ky)
#pragma unroll
              for (int kx = 0; kx < 3; ++kx)
                a = fmaf(xin[dy + ky][dx + kx], wv1[oc][ky * 3 + kx], a);
            best = fmaxf(best, a);
          }
        p1[oc][gl][px + 1] = validG ? best : 0.f;
      }
    }
    __syncthreads();

    // ---- conv2 partial: ic' 0..3 of this group, all 4 needed oc ----
#pragma unroll 1
    for (int ic = 0; ic < 4; ++ic) {
      float xin[4][4];
#pragma unroll
      for (int r = 0; r < 4; ++r)
#pragma unroll
        for (int c = 0; c < 4; ++c)
          xin[r][c] = p1[ic][2 * py2l + r][2 * px2 + c];
#pragma unroll
      for (int oc = 0; oc < 4; ++oc) {
        const float* wp = &w2s[(oc * 8 + 4 * g + ic) * 9];  // broadcast ds_read
#pragma unroll
        for (int dy = 0; dy < 2; ++dy)
#pragma unroll
          for (int dx = 0; dx < 2; ++dx) {
#pragma unroll
            for (int ky = 0; ky < 3; ++ky)
#pragma unroll
              for (int kx = 0; kx < 3; ++kx)
                acc[oc][dy][dx] =
                    fmaf(xin[dy + ky][dx + kx], wp[ky * 3 + kx], acc[oc][dy][dx]);
          }
      }
    }
  }

  // ---- ReLU + 2x2 pool + spatial partial-sum ----
  const int lane = tid & 63, w = tid >> 6;
#pragma unroll
  for (int oc = 0; oc < 4; ++oc) {
    float p = fmaxf(fmaxf(fmaxf(acc[oc][0][0], acc[oc][0][1]),
                          fmaxf(acc[oc][1][0], acc[oc][1][1])), 0.f);
#pragma unroll
    for (int off = 32; off > 0; off >>= 1) p += __shfl_down(p, off);
    if (lane == 0) wred[w][oc] = p;
  }
  __syncthreads();
  if (tid < 4) {
    float s = wred[0][tid] + wred[1][tid] + wred[2][tid] + wred[3][tid];
    partials[((size_t)b * 4 + q) * 4 + tid] = s;
  }
}

// ---------------------------------------------------------------------------
// K3: feats -> quantum circuit -> batchnorm (over batch=512) -> head.
// Single block, 512 threads; thread = batch element. Shuffle reductions.
// ---------------------------------------------------------------------------
__global__ __launch_bounds__(512) void k3_tail(
    const float* __restrict__ partials, const float* __restrict__ qp,
    const float* __restrict__ gamma, const float* __restrict__ beta,
    const float* __restrict__ hw, const float* __restrict__ hb,
    float* __restrict__ out) {
  __shared__ float wsum[8][8];
  __shared__ float stats[8];
  const int tid = threadIdx.x;  // batch index

  // partials[tid][0..15] = 4 strips x 4 oc, contiguous 64B -> 4x dwordx4.
  const f4* pp = (const f4*)(partials + tid * 16);
  f4 s0 = pp[0], s1 = pp[1], s2 = pp[2], s3 = pp[3];
  float f[4];
  f[0] = (s0.x + s1.x + s2.x + s3.x) * (1.f / 1024.f);
  f[1] = (s0.y + s1.y + s2.y + s3.y) * (1.f / 1024.f);
  f[2] = (s0.z + s1.z + s2.z + s3.z) * (1.f / 1024.f);
  f[3] = (s0.w + s1.w + s2.w + s3.w) * (1.f / 1024.f);

  // Per-wire single-qubit amplitudes: a0 = cx*cy - i*sx*sy, a1 = cx*sy - i*sx*cy
  float a0r[4], a0i[4], a1r[4], a1i[4];
#pragma unroll
  for (int i = 0; i < 4; ++i) {
    float cy, sy, cx, sx;
    __sincosf(0.5f * f[i], &sy, &cy);
    __sincosf(0.5f * uload(qp + i), &sx, &cx);
    a0r[i] = cx * cy; a0i[i] = -sx * sy;
    a1r[i] = cx * sy; a1i[i] = -sx * cy;
  }

  // psi[j] = prod over wires of a_{bit}(wire), wire 0 = MSB
  float pr[16], pi[16];
#pragma unroll
  for (int j = 0; j < 16; ++j) {
    float rr = 1.f, ii = 0.f;
#pragma unroll
    for (int w = 0; w < 4; ++w) {
      int bit = (j >> (3 - w)) & 1;
      float ar = bit ? a1r[w] : a0r[w];
      float ai = bit ? a1i[w] : a0i[w];
      float t = rr * ar - ii * ai;
      ii = rr * ai + ii * ar;
      rr = t;
    }
    pr[j] = rr; pi[j] = ii;
  }

  // Composed CNOT(0,1);CNOT(1,2);CNOT(2,3) permutation (new[j] = old[comp[j]])
  constexpr int comp[16] = {0, 1, 3, 2, 6, 7, 5, 4, 12, 13, 15, 14, 10, 11, 9, 8};
  float qv[4] = {0.f, 0.f, 0.f, 0.f};
#pragma unroll
  for (int j = 0; j < 16; ++j) {
    int s = comp[j];
    float p = pr[s] * pr[s] + pi[s] * pi[s];
#pragma unroll
    for (int i = 0; i < 4; ++i)
      qv[i] += ((j >> (3 - i)) & 1) ? -p : p;
  }

  // Batch sums of q and q^2 via wave shuffles, then cross-wave LDS combine.
  float v[8];
#pragma unroll
  for (int i = 0; i < 4; ++i) { v[i] = qv[i]; v[4 + i] = qv[i] * qv[i]; }
#pragma unroll
  for (int k = 0; k < 8; ++k)
#pragma unroll
    for (int off = 32; off > 0; off >>= 1) v[k] += __shfl_down(v[k], off);
  const int lane = tid & 63, w = tid >> 6;
  if (lane == 0) {
#pragma unroll
    for (int k = 0; k < 8; ++k) wsum[w][k] = v[k];
  }
  __syncthreads();
  if (tid < 8) {
    float s = 0.f;
#pragma unroll
    for (int ww = 0; ww < 8; ++ww) s += wsum[ww][tid];
    stats[tid] = s * (1.f / 512.f);
  }
  __syncthreads();

  float nm[4];
#pragma unroll
  for (int i = 0; i < 4; ++i) {
    float mu  = stats[i];
    float var = stats[4 + i] - mu * mu;
    nm[i] = uload(gamma + i) * (qv[i] - mu) * rsqrtf(var + EPS) + uload(beta + i);
  }
#pragma unroll
  for (int k = 0; k < 4; ++k) {
    float o = uload(hb + k);
#pragma unroll
    for (int i = 0; i < 4; ++i) o = fmaf(nm[i], uload(hw + k * 4 + i), o);
    out[tid * 4 + k] = o;
  }
}

extern "C" void kernel_launch(void* const* d_in, const int* in_sizes, int n_in,
                              void* d_out, int out_size, void* d_ws, size_t ws_size,
                              hipStream_t stream) {
  const float* x  = (const float*)d_in[0];
  const float* w1 = (const float*)d_in[1];
  const float* b1 = (const float*)d_in[2];
  const float* w2 = (const float*)d_in[3];
  const float* b2 = (const float*)d_in[4];
  const float* qp = (const float*)d_in[5];
  const float* gm = (const float*)d_in[6];
  const float* bt = (const float*)d_in[7];
  const float* hw = (const float*)d_in[8];
  const float* hb = (const float*)d_in[9];
  float* out = (float*)d_out;

  float* partials = (float*)d_ws;  // 512 * 4 strips * 4 oc floats = 32 KB

  k12_fused<<<512 * 4, 256, 0, stream>>>(x, w1, b1, w2, b2, partials);
  k3_tail<<<1, 512, 0, stream>>>(partials, qp, gm, bt, hw, hb, out);
}